// Round 5
// baseline (704.195 us; speedup 1.0000x reference)
//
#include <hip/hip_runtime.h>
#include <stdint.h>

#define T_TOK 8192
#define NEXP  8
#define DIMSZ 1024
#define HIDSZ 2048

typedef __attribute__((ext_vector_type(4))) float f32x4;
typedef __attribute__((ext_vector_type(8))) short s16x8;

// ---------- helpers ----------

__device__ __forceinline__ uint16_t f2bf(float f) {
  uint32_t u = __builtin_bit_cast(uint32_t, f);
  u += 0x7fffu + ((u >> 16) & 1u);   // RNE
  return (uint16_t)(u >> 16);
}

// packed f32x2 -> bf16x2 (RNE); low word = a.
__device__ __forceinline__ uint32_t pkbf(float a, float b) {
  return (uint32_t)f2bf(a) | ((uint32_t)f2bf(b) << 16);
}

// async global->LDS, 16B per lane; LDS dst = wave-uniform base + lane*16.
__device__ __forceinline__ void gload_lds16(const uint16_t* g, const uint16_t* lds_base) {
  __builtin_amdgcn_global_load_lds(
      (const __attribute__((address_space(1))) uint32_t*)(uintptr_t)g,
      (__attribute__((address_space(3))) uint32_t*)(uint32_t)(uintptr_t)lds_base,
      16, 0, 0);
}

// ---------- convert x only (+ offsets in block 0) ----------

__global__ void cvt_x(const float* __restrict__ x, uint16_t* __restrict__ xb,
                      const int* __restrict__ counts, int* __restrict__ offs,
                      int* __restrict__ toffs) {
  if (blockIdx.x == 0 && threadIdx.x == 0) {
    int s = 0, ts = 0;
    for (int e = 0; e < NEXP; ++e) {
      offs[e] = s; toffs[e] = ts;
      s += counts[e]; ts += (counts[e] + 127) >> 7;
    }
    offs[NEXP] = s; toffs[NEXP] = ts;
  }
  const size_t i = blockIdx.x * (size_t)blockDim.x + threadIdx.x;
  const float4* p = (const float4*)x + 4 * i;
  float4 a = p[0], b = p[1], c = p[2], d = p[3];
  uint4 o0, o1;
  o0.x = pkbf(a.x, a.y); o0.y = pkbf(a.z, a.w);
  o0.z = pkbf(b.x, b.y); o0.w = pkbf(b.z, b.w);
  o1.x = pkbf(c.x, c.y); o1.y = pkbf(c.z, c.w);
  o1.z = pkbf(d.x, d.y); o1.w = pkbf(d.z, d.w);
  uint4* q = (uint4*)xb + 2 * i;
  q[0] = o0;
  q[1] = o1;
}

// ---------- grouped NT GEMM, A-double-buffered pipeline, fused B f32->bf16 ----------
// C[m,n] = sum_k A[m,k] * B_e[n,k].  Tile 128x128, BK=64, 4 waves (2x2).
// As0/As1 are DISTINCT shared arrays (compile-time selection via macro) so the
// compiler can prove the MFMA-phase ds_reads don't alias the in-flight
// global_load_lds writes -> no vmcnt drain before compute (R4's failure mode).
// Per step: issue B reg-loads(t+1) + A gloads(t+1)->alt buf, MFMA(t),
// barrier (drains gloads, covered by MFMA), cvt+ds_write B(t+1), barrier.
// T1 bijective XCD remap (proven: FETCH 172->102 MB).
// LDS rows: 64 bf16 = 8 x 16B chunks; chunk Q of row R at position
// Q ^ ((R>>1)&7)  => ds_read_b128 fragment reads are <=2-way (free).
template <bool OUT_BF16>
__global__ __launch_bounds__(256, 3)
void gemm_grouped(const uint16_t* __restrict__ A, const float* __restrict__ B,
                  void* __restrict__ C, const int* __restrict__ offs,
                  const int* __restrict__ toffs, int N, int K, int lognt) {
  __shared__ __align__(16) uint16_t As0[128 * 64];  // 16 KB
  __shared__ __align__(16) uint16_t As1[128 * 64];  // 16 KB
  __shared__ __align__(16) uint16_t Bs[128 * 64];   // 16 KB

  // T1: bijective XCD-chunked remap (valid for any nwg).
  const int nwg  = gridDim.x;
  const int orig = blockIdx.x;
  const int qc = nwg >> 3, rc = nwg & 7, xcd = orig & 7;
  const int bid = (xcd < rc ? xcd * (qc + 1) : rc * (qc + 1) + (xcd - rc) * qc) + (orig >> 3);

  const int mtg = bid >> lognt;
  const int nt  = bid & ((1 << lognt) - 1);
  if (mtg >= toffs[NEXP]) return;
  int e = 0;
#pragma unroll
  for (int i = 1; i < NEXP; ++i) e += (toffs[i] <= mtg) ? 1 : 0;
  const int mt      = mtg - toffs[e];
  const int m_start = offs[e];
  const int m_count = offs[e + 1] - m_start;
  const int m0      = mt * 128;
  int valid_m = m_count - m0;
  if (valid_m > 128) valid_m = 128;
  const int n0 = nt * 128;

  const int tid  = threadIdx.x;
  const int w    = tid >> 6;
  const int lane = tid & 63;
  const int wm = w & 1, wn = w >> 1;

  const uint16_t* gA = A + (size_t)m_start * K;
  const float*    gB = B + (size_t)e * N * K;

  // A staging (gload_lds, pre-swizzled source): wave w owns rows [w*32,w*32+32),
  // call c covers rows w*32+c*8+[0,8). Lane l -> row +(l>>3), LDS chunk pos l&7,
  // which must hold global chunk (l&7) ^ ((row>>1)&7).
  const uint16_t* ap[4];
#pragma unroll
  for (int c = 0; c < 4; ++c) {
    const int r  = w * 32 + c * 8 + (lane >> 3);
    const int q8 = ((lane & 7) ^ ((r >> 1) & 7)) * 8;
    const int ra = (r < valid_m) ? r : (valid_m - 1);
    ap[c] = gA + (size_t)(m0 + ra) * K + q8;
  }

  // B staging (reg path, natural source chunk q=lane&7, swizzled LDS write pos).
  const float* bp[4];
  int bwoff[4];
#pragma unroll
  for (int c = 0; c < 4; ++c) {
    const int r = w * 32 + c * 8 + (lane >> 3);
    bp[c] = gB + (size_t)(n0 + r) * K + (lane & 7) * 8;
    bwoff[c] = r * 64 + (((lane & 7) ^ ((r >> 1) & 7)) * 8);
  }

  // Fragment read (swizzled): row = band + fr; k-half kk: offset f0 ^ (kk*32).
  const int fr = lane & 15;
  const int f0 = ((lane >> 4) ^ ((fr >> 1) & 7)) * 8;

  f32x4 acc[4][4];
#pragma unroll
  for (int mi = 0; mi < 4; ++mi)
#pragma unroll
    for (int ni = 0; ni < 4; ++ni) acc[mi][ni] = (f32x4){0.f, 0.f, 0.f, 0.f};

  float4 bq[8];
  const int NT = K >> 6;

  // ---- prologue: stage tile 0 (A -> As0, B -> Bs) ----
#pragma unroll
  for (int c = 0; c < 4; ++c) {
    bq[2 * c]     = *(const float4*)bp[c];
    bq[2 * c + 1] = *(const float4*)(bp[c] + 4);
    bp[c] += 64;
  }
#pragma unroll
  for (int c = 0; c < 4; ++c) {
    gload_lds16(ap[c], &As0[(w * 32 + c * 8) * 64]);
    ap[c] += 64;
  }
#pragma unroll
  for (int c = 0; c < 4; ++c) {
    uint4 o;
    o.x = pkbf(bq[2 * c].x,     bq[2 * c].y);
    o.y = pkbf(bq[2 * c].z,     bq[2 * c].w);
    o.z = pkbf(bq[2 * c + 1].x, bq[2 * c + 1].y);
    o.w = pkbf(bq[2 * c + 1].z, bq[2 * c + 1].w);
    *(uint4*)&Bs[bwoff[c]] = o;
  }
  __syncthreads();

  // One pipeline step with compile-time buffer names.
#define STEP(AR, AW, T)                                                         \
  {                                                                             \
    const bool more = ((T) + 1 < NT);                                           \
    if (more) {                                                                 \
      _Pragma("unroll")                                                         \
      for (int c = 0; c < 4; ++c) {                                             \
        bq[2 * c]     = *(const float4*)bp[c];                                  \
        bq[2 * c + 1] = *(const float4*)(bp[c] + 4);                            \
        bp[c] += 64;                                                            \
      }                                                                         \
      _Pragma("unroll")                                                         \
      for (int c = 0; c < 4; ++c) {                                             \
        gload_lds16(ap[c], &AW[(w * 32 + c * 8) * 64]);                         \
        ap[c] += 64;                                                            \
      }                                                                         \
    }                                                                           \
    _Pragma("unroll")                                                           \
    for (int kk = 0; kk < 2; ++kk) {                                            \
      const int fk = f0 ^ (kk << 5);                                            \
      s16x8 af[4], bf[4];                                                       \
      _Pragma("unroll")                                                         \
      for (int mi = 0; mi < 4; ++mi)                                            \
        af[mi] = *(const s16x8*)&AR[(wm * 64 + mi * 16 + fr) * 64 + fk];        \
      _Pragma("unroll")                                                         \
      for (int ni = 0; ni < 4; ++ni)                                            \
        bf[ni] = *(const s16x8*)&Bs[(wn * 64 + ni * 16 + fr) * 64 + fk];        \
      _Pragma("unroll")                                                         \
      for (int mi = 0; mi < 4; ++mi)                                            \
        _Pragma("unroll")                                                       \
        for (int ni = 0; ni < 4; ++ni)                                          \
          acc[mi][ni] = __builtin_amdgcn_mfma_f32_16x16x32_bf16(                \
              af[mi], bf[ni], acc[mi][ni], 0, 0, 0);                            \
    }                                                                           \
    if (more) {                                                                 \
      __syncthreads();  /* drains gloads (covered by MFMA); Bs read done */     \
      _Pragma("unroll")                                                         \
      for (int c = 0; c < 4; ++c) {                                             \
        uint4 o;                                                                \
        o.x = pkbf(bq[2 * c].x,     bq[2 * c].y);                               \
        o.y = pkbf(bq[2 * c].z,     bq[2 * c].w);                               \
        o.z = pkbf(bq[2 * c + 1].x, bq[2 * c + 1].y);                           \
        o.w = pkbf(bq[2 * c + 1].z, bq[2 * c + 1].w);                           \
        *(uint4*)&Bs[bwoff[c]] = o;                                             \
      }                                                                         \
      __syncthreads();  /* B(t+1) visible; nothing outstanding */               \
    }                                                                           \
  }

  for (int t = 0; t < NT; t += 2) {
    STEP(As0, As1, t);
    STEP(As1, As0, t + 1);
  }
#undef STEP

  // Epilogue. C/D 16x16 layout: col = lane&15, row = (lane>>4)*4 + reg.
  const int cq = (lane >> 4) * 4;
  const int cc = lane & 15;
#pragma unroll
  for (int mi = 0; mi < 4; ++mi) {
#pragma unroll
    for (int r = 0; r < 4; ++r) {
      const int rt = wm * 64 + mi * 16 + cq + r;
      if (rt < valid_m) {
        const size_t rowoff = (size_t)(m_start + m0 + rt) * N;
#pragma unroll
        for (int ni = 0; ni < 4; ++ni) {
          const int col = n0 + wn * 64 + ni * 16 + cc;
          const float v = acc[mi][ni][r];
          if (OUT_BF16) {
            ((uint16_t*)C)[rowoff + col] = f2bf(v);
          } else {
            const uint32_t b = (uint32_t)f2bf(v) << 16;
            ((float*)C)[rowoff + col] = __builtin_bit_cast(float, b);
          }
        }
      }
    }
  }
}

// ---------- launch ----------

extern "C" void kernel_launch(void* const* d_in, const int* in_sizes, int n_in,
                              void* d_out, int out_size, void* d_ws, size_t ws_size,
                              hipStream_t stream) {
  const float* x  = (const float*)d_in[0];   // [T, DIM]
  const float* w1 = (const float*)d_in[1];   // [E, HID, DIM]
  const float* w2 = (const float*)d_in[2];   // [E, DIM, HID]
  const int* cnt  = (const int*)d_in[3];     // [E]
  float* out = (float*)d_out;                // [T, DIM] f32

  char* ws = (char*)d_ws;
  uint16_t* xb = (uint16_t*)(ws);                       // 16 MB  [T, DIM] bf16
  uint16_t* h  = (uint16_t*)(ws + 16777216);            // 32 MB  [T, HID] bf16
  int* offs    = (int*)(ws + 50331648);                 // 9 ints
  int* toffs   = offs + 9;                              // 9 ints

  cvt_x<<<2048, 256, 0, stream>>>(x, xb, cnt, offs, toffs);

  const int MAX_MT = T_TOK / 128 + NEXP - 1;            // 71: worst-case m-tiles

  // GEMM1: h = xb @ w1^T  (N=HID=2048 -> 16 n-tiles, lognt=4, K=DIM)
  gemm_grouped<true><<<MAX_MT * 16, 256, 0, stream>>>(
      xb, w1, (void*)h, offs, toffs, HIDSZ, DIMSZ, 4);

  // GEMM2: out = h @ w2^T  (N=DIM=1024 -> 8 n-tiles, lognt=3, K=HID)
  gemm_grouped<false><<<MAX_MT * 8, 256, 0, stream>>>(
      h, w2, (void*)out, offs, toffs, DIMSZ, HIDSZ, 3);
}

// Round 6
// 277.900 us; speedup vs baseline: 2.5340x; 2.5340x over previous
//
#include <hip/hip_runtime.h>
#include <stdint.h>

#define T_TOK 8192
#define NEXP  8
#define DIMSZ 1024
#define HIDSZ 2048

typedef __attribute__((ext_vector_type(4))) float f32x4;
typedef __attribute__((ext_vector_type(8))) short s16x8;

// ---------- helpers ----------

__device__ __forceinline__ uint16_t f2bf(float f) {
  uint32_t u = __builtin_bit_cast(uint32_t, f);
  u += 0x7fffu + ((u >> 16) & 1u);   // RNE
  return (uint16_t)(u >> 16);
}

__device__ __forceinline__ uint32_t pkbf(float a, float b) {
  return (uint32_t)f2bf(a) | ((uint32_t)f2bf(b) << 16);
}

// convert one 16-float unit (64B read, 32B write)
__device__ __forceinline__ void cvt_unit(const float* __restrict__ src,
                                         uint16_t* __restrict__ dst, size_t j) {
  const float4* p = (const float4*)src + 4 * j;
  float4 a = p[0], b = p[1], c = p[2], d = p[3];
  uint4 o0, o1;
  o0.x = pkbf(a.x, a.y); o0.y = pkbf(a.z, a.w);
  o0.z = pkbf(b.x, b.y); o0.w = pkbf(b.z, b.w);
  o1.x = pkbf(c.x, c.y); o1.y = pkbf(c.z, c.w);
  o1.z = pkbf(d.x, d.y); o1.w = pkbf(d.z, d.w);
  uint4* q = (uint4*)dst + 2 * j;
  q[0] = o0;
  q[1] = o1;
}

// async global->LDS, 16B per lane; LDS dst = wave-uniform base + lane*16.
__device__ __forceinline__ void gload_lds16(const uint16_t* g, const uint16_t* lds_base) {
  __builtin_amdgcn_global_load_lds(
      (const __attribute__((address_space(1))) uint32_t*)(uintptr_t)g,
      (__attribute__((address_space(3))) uint32_t*)(uint32_t)(uintptr_t)lds_base,
      16, 0, 0);
}

// ---------- convert x + w1 (+ offsets in block 0) ----------
// w2 is converted by piggyback blocks inside the GEMM1 dispatch.
// 96 MB read + 48 MB write. Grid 2048x256: exactly 3 units/thread.

__global__ void cvt_xw1(const float* __restrict__ x, const float* __restrict__ w1,
                        uint16_t* __restrict__ xb, uint16_t* __restrict__ w1b,
                        const int* __restrict__ counts, int* __restrict__ offs,
                        int* __restrict__ toffs) {
  if (blockIdx.x == 0 && threadIdx.x == 0) {
    int s = 0, ts = 0;
    for (int e = 0; e < NEXP; ++e) {
      offs[e] = s; toffs[e] = ts;
      s += counts[e]; ts += (counts[e] + 127) >> 7;
    }
    offs[NEXP] = s; toffs[NEXP] = ts;
  }
  const int NX = (T_TOK * DIMSZ) / 16;           // 524288
  const int NW = (NEXP * HIDSZ * DIMSZ) / 16;    // 1048576
  const int total = NX + NW;
  const int stride = gridDim.x * blockDim.x;
  for (int i = blockIdx.x * blockDim.x + threadIdx.x; i < total; i += stride) {
    if (i < NX) cvt_unit(x, xb, i);
    else        cvt_unit(w1, w1b, i - NX);
  }
}

// ---------- grouped NT GEMM (R1 structure: proven 270us base) ----------
// C[m,n] = sum_k A[m,k] * B_e[n,k].  Tile 128x128, BK=64, 4 waves (2x2),
// both operands staged bf16 via global_load_lds w=16, 2 barriers per K-step.
// NEW vs R1: (a) T1 bijective XCD-chunked blockIdx remap (proven FETCH
// 172->102 MB in R4's counters); (b) optional piggyback: first `ncvt` blocks
// convert w2 f32->bf16 instead of doing GEMM work (hides under GEMM1's ~30%
// HBM utilization; GEMM2 consumes w2b only after this kernel completes).
// LDS rows: 64 bf16 = 8 x 16B chunks; chunk Q of row R at position
// Q ^ ((R>>1)&7)  => ds_read_b128 fragment reads are <=2-way (free).
template <bool OUT_BF16>
__global__ __launch_bounds__(256, 3)
void gemm_grouped(const uint16_t* __restrict__ A, const uint16_t* __restrict__ B,
                  void* __restrict__ C, const int* __restrict__ offs,
                  const int* __restrict__ toffs, int N, int K, int lognt,
                  const float* __restrict__ cvt_src, uint16_t* __restrict__ cvt_dst,
                  int ncvt, int cvt_units) {
  __shared__ __align__(16) uint16_t As[128 * 64];  // 16 KB
  __shared__ __align__(16) uint16_t Bs[128 * 64];  // 16 KB

  // ---- piggyback conversion blocks ----
  if (blockIdx.x < (unsigned)ncvt) {
    const int cstride = ncvt * 256;
    for (int u = blockIdx.x * 256 + threadIdx.x; u < cvt_units; u += cstride)
      cvt_unit(cvt_src, cvt_dst, u);
    return;
  }

  // ---- T1: bijective XCD-chunked remap over the gemm-block range ----
  const int nb   = gridDim.x - ncvt;
  const int orig = blockIdx.x - ncvt;
  const int qc = nb >> 3, rc = nb & 7, xcd = orig & 7;
  const int bid = (xcd < rc ? xcd * (qc + 1) : rc * (qc + 1) + (xcd - rc) * qc) + (orig >> 3);

  const int mtg = bid >> lognt;
  const int nt  = bid & ((1 << lognt) - 1);
  if (mtg >= toffs[NEXP]) return;
  int e = 0;
#pragma unroll
  for (int i = 1; i < NEXP; ++i) e += (toffs[i] <= mtg) ? 1 : 0;
  const int mt      = mtg - toffs[e];
  const int m_start = offs[e];
  const int m_count = offs[e + 1] - m_start;
  const int m0      = mt * 128;
  int valid_m = m_count - m0;
  if (valid_m > 128) valid_m = 128;
  const int n0 = nt * 128;

  const int tid  = threadIdx.x;
  const int w    = tid >> 6;
  const int lane = tid & 63;
  const int wm = w & 1, wn = w >> 1;

  const uint16_t* gA = A + (size_t)m_start * K;
  const uint16_t* gB = B + (size_t)e * N * K;

  // Staging: wave w owns rows [w*32, w*32+32). Call c covers rows w*32+c*8+[0,8).
  // Lane l lands at LDS row +(l>>3), chunk pos l&7, which must hold global
  // chunk Q = (l&7) ^ ((row>>1)&7).
  const uint16_t* ap[4];
  const uint16_t* bp[4];
#pragma unroll
  for (int c = 0; c < 4; ++c) {
    const int r  = w * 32 + c * 8 + (lane >> 3);
    const int q8 = ((lane & 7) ^ ((r >> 1) & 7)) * 8;
    const int ra = (r < valid_m) ? r : (valid_m - 1);
    ap[c] = gA + (size_t)(m0 + ra) * K + q8;
    bp[c] = gB + (size_t)(n0 + r) * K + q8;
  }

  // Fragment read (swizzled): row = band + fr; k-half kk: offset f0 ^ (kk*32).
  const int fr = lane & 15;
  const int f0 = ((lane >> 4) ^ ((fr >> 1) & 7)) * 8;

  f32x4 acc[4][4];
#pragma unroll
  for (int mi = 0; mi < 4; ++mi)
#pragma unroll
    for (int ni = 0; ni < 4; ++ni) acc[mi][ni] = (f32x4){0.f, 0.f, 0.f, 0.f};

  for (int k0 = 0; k0 < K; k0 += 64) {
    __syncthreads();
#pragma unroll
    for (int c = 0; c < 4; ++c) {
      gload_lds16(ap[c], &As[(w * 32 + c * 8) * 64]);
      gload_lds16(bp[c], &Bs[(w * 32 + c * 8) * 64]);
    }
#pragma unroll
    for (int c = 0; c < 4; ++c) { ap[c] += 64; bp[c] += 64; }
    __syncthreads();

#pragma unroll
    for (int kk = 0; kk < 2; ++kk) {
      const int fk = f0 ^ (kk << 5);
      s16x8 af[4], bf[4];
#pragma unroll
      for (int mi = 0; mi < 4; ++mi)
        af[mi] = *(const s16x8*)&As[(wm * 64 + mi * 16 + fr) * 64 + fk];
#pragma unroll
      for (int ni = 0; ni < 4; ++ni)
        bf[ni] = *(const s16x8*)&Bs[(wn * 64 + ni * 16 + fr) * 64 + fk];
#pragma unroll
      for (int mi = 0; mi < 4; ++mi)
#pragma unroll
        for (int ni = 0; ni < 4; ++ni)
          acc[mi][ni] = __builtin_amdgcn_mfma_f32_16x16x32_bf16(af[mi], bf[ni], acc[mi][ni], 0, 0, 0);
    }
  }

  // Epilogue. C/D 16x16 layout: col = lane&15, row = (lane>>4)*4 + reg.
  const int cq = (lane >> 4) * 4;
  const int cc = lane & 15;
#pragma unroll
  for (int mi = 0; mi < 4; ++mi) {
#pragma unroll
    for (int r = 0; r < 4; ++r) {
      const int rt = wm * 64 + mi * 16 + cq + r;
      if (rt < valid_m) {
        const size_t rowoff = (size_t)(m_start + m0 + rt) * N;
#pragma unroll
        for (int ni = 0; ni < 4; ++ni) {
          const int col = n0 + wn * 64 + ni * 16 + cc;
          const float v = acc[mi][ni][r];
          if (OUT_BF16) {
            ((uint16_t*)C)[rowoff + col] = f2bf(v);
          } else {
            const uint32_t b = (uint32_t)f2bf(v) << 16;
            ((float*)C)[rowoff + col] = __builtin_bit_cast(float, b);
          }
        }
      }
    }
  }
}

// ---------- launch ----------

extern "C" void kernel_launch(void* const* d_in, const int* in_sizes, int n_in,
                              void* d_out, int out_size, void* d_ws, size_t ws_size,
                              hipStream_t stream) {
  const float* x  = (const float*)d_in[0];   // [T, DIM]
  const float* w1 = (const float*)d_in[1];   // [E, HID, DIM]
  const float* w2 = (const float*)d_in[2];   // [E, DIM, HID]
  const int* cnt  = (const int*)d_in[3];     // [E]
  float* out = (float*)d_out;                // [T, DIM] f32

  char* ws = (char*)d_ws;
  uint16_t* xb  = (uint16_t*)(ws);                      // 16 MB  [T, DIM] bf16
  uint16_t* w1b = (uint16_t*)(ws + 16777216);           // 32 MB  [E, HID, DIM] bf16
  uint16_t* w2b = (uint16_t*)(ws + 50331648);           // 32 MB  [E, DIM, HID] bf16
  uint16_t* h   = (uint16_t*)(ws + 83886080);           // 32 MB  [T, HID] bf16
  int* offs     = (int*)(ws + 117440512);               // 9 ints
  int* toffs    = offs + 9;                             // 9 ints

  cvt_xw1<<<2048, 256, 0, stream>>>(x, w1, xb, w1b, cnt, offs, toffs);

  const int MAX_MT = T_TOK / 128 + NEXP - 1;            // 71: worst-case m-tiles
  const int NCVT   = 512;                               // piggyback w2-cvt blocks
  const int W2U    = (NEXP * DIMSZ * HIDSZ) / 16;       // 1048576 16-float units

  // GEMM1: h = xb @ w1b^T  (N=HID=2048 -> 16 n-tiles, lognt=4, K=DIM)
  // + piggybacked w2 conversion in the first NCVT blocks.
  gemm_grouped<true><<<NCVT + MAX_MT * 16, 256, 0, stream>>>(
      xb, w1b, (void*)h, offs, toffs, HIDSZ, DIMSZ, 4, w2, w2b, NCVT, W2U);

  // GEMM2: out = h @ w2b^T  (N=DIM=1024 -> 8 n-tiles, lognt=3, K=HID)
  gemm_grouped<false><<<MAX_MT * 8, 256, 0, stream>>>(
      h, w2b, (void*)out, offs, toffs, DIMSZ, HIDSZ, 3, (const float*)nullptr,
      (uint16_t*)nullptr, 0, 0);
}